// Round 2
// baseline (29203.726 us; speedup 1.0000x reference)
//
#include <hip/hip_runtime.h>

#define N_ 1024
#define D_ 128
#define K_ 256
#define M_ 4
#define H_ 256
#define NB_ 2
#define JT 64          // j-tile staged in LDS
#define W2PAD 132      // padded row (16B-aligned rows, breaks bank alignment)

// ---------------------------------------------------------------------------
// Kernel 1: Bb[m,k,d] = B only (f32-rounded exact sum of f32 products)
// B[k,d] = sum_d' cb[k,d'] * cp_w[m, d, D+d']
// ---------------------------------------------------------------------------
__global__ void precompute_Bb(const float* __restrict__ base_cb,
                              const float* __restrict__ cp_w,
                              float* __restrict__ Bb) {
    const int mk = blockIdx.x;          // m*K + k
    const int m  = mk >> 8;
    const int d  = threadIdx.x;         // 0..127
    const float* cb = base_cb + (size_t)mk * D_;
    const float* wc = cp_w + ((size_t)(m * D_ + d)) * (2 * D_) + D_;
    double a0 = 0, a1 = 0, a2 = 0, a3 = 0;
    #pragma unroll
    for (int dp = 0; dp < D_; dp += 4) {
        a0 += (double)(cb[dp + 0] * wc[dp + 0]);
        a1 += (double)(cb[dp + 1] * wc[dp + 1]);
        a2 += (double)(cb[dp + 2] * wc[dp + 2]);
        a3 += (double)(cb[dp + 3] * wc[dp + 3]);
    }
    Bb[(size_t)mk * D_ + d] = (float)((a0 + a1) + (a2 + a3));
}

// ---------------------------------------------------------------------------
// Kernel 2: one workgroup per n, thread t = codeword k.
// All reductions in f64 over f32 products; f32 rounding at the reference's
// materialization points (A, B, h, C, dist).
// ---------------------------------------------------------------------------
__launch_bounds__(256, 1)
__global__ void qinco_main(const float* __restrict__ z,
                           const float* __restrict__ cp_w,
                           const float* __restrict__ cp_b,
                           const float* __restrict__ w1,
                           const float* __restrict__ b1,
                           const float* __restrict__ w2,
                           const float* __restrict__ b2,
                           const float* __restrict__ Bb,
                           float* __restrict__ out0,   // z_q_st  (N,D)
                           float* __restrict__ out1,   // codes   (N,M) as float
                           float* __restrict__ out2,   // residuals (M,N,D)
                           float* __restrict__ out3) { // centroids (M,N,D)
    __shared__ float sxhat[D_];
    __shared__ float sA[D_];
    __shared__ float sr[D_];
    __shared__ float scb[D_];
    __shared__ float sdist[K_];
    __shared__ float scsel[D_];
    __shared__ float sw2t[JT][W2PAD];
    __shared__ int   scode;

    const int n = blockIdx.x;
    const int t = threadIdx.x;
    const int k = t;

    if (t < D_) sxhat[t] = 0.0f;
    __syncthreads();

    float cold[D_];

    for (int m = 0; m < M_; ++m) {
        // ---- r = z - x_hat ; A = x_hat @ Wx^T (f64 sum of f32 products) ----
        if (t < D_) {
            scb[t] = cp_b[m * D_ + t];
            float zv = z[n * D_ + t];
            float rv = zv - sxhat[t];
            sr[t] = rv;
            out2[((size_t)m * N_ + n) * D_ + t] = rv;
            const float* wx = cp_w + ((size_t)(m * D_ + t)) * (2 * D_);
            double a0 = 0, a1 = 0, a2 = 0, a3 = 0;
            #pragma unroll
            for (int dp = 0; dp < D_; dp += 4) {
                a0 += (double)(sxhat[dp + 0] * wx[dp + 0]);
                a1 += (double)(sxhat[dp + 1] * wx[dp + 1]);
                a2 += (double)(sxhat[dp + 2] * wx[dp + 2]);
                a3 += (double)(sxhat[dp + 3] * wx[dp + 3]);
            }
            sA[t] = (float)((a0 + a1) + (a2 + a3));
        }
        __syncthreads();

        // ---- C init: (A + B) + cp_b, f32 adds in reference order ----
        const float* bbrow = Bb + ((size_t)(m * K_ + k)) * D_;
        #pragma unroll
        for (int d = 0; d < D_; d += 4) {
            float4 bv = *reinterpret_cast<const float4*>(bbrow + d);
            cold[d + 0] = (sA[d + 0] + bv.x) + scb[d + 0];
            cold[d + 1] = (sA[d + 1] + bv.y) + scb[d + 1];
            cold[d + 2] = (sA[d + 2] + bv.z) + scb[d + 2];
            cold[d + 3] = (sA[d + 3] + bv.w) + scb[d + 3];
        }

        // ---- residual MLP blocks ----
        for (int i = 0; i < NB_; ++i) {
            const int bi = m * NB_ + i;
            const float* w1p = w1 + (size_t)bi * H_ * D_;
            const float* b1p = b1 + (size_t)bi * H_;
            const float* w2p = w2 + (size_t)bi * D_ * H_;
            const float* b2p = b2 + (size_t)bi * D_;

            double dacc[D_];
            #pragma unroll
            for (int d = 0; d < D_; ++d) dacc[d] = 0.0;

            for (int j0 = 0; j0 < H_; j0 += JT) {
                // stage w2 tile transposed: sw2t[jj][d] = w2p[d][j0+jj]
                __syncthreads();   // protect previous tile contents
                {
                    const int jj = t & 63;
                    const int d0 = (t >> 6) * 32;
                    #pragma unroll 8
                    for (int dd = 0; dd < 32; ++dd)
                        sw2t[jj][d0 + dd] = w2p[(size_t)(d0 + dd) * H_ + j0 + jj];
                }
                __syncthreads();

                for (int jj = 0; jj < JT; ++jj) {
                    const int j = j0 + jj;
                    const float* w1r = w1p + (size_t)j * D_;
                    double h0 = 0, h1 = 0, h2 = 0, h3 = 0;
                    #pragma unroll
                    for (int d = 0; d < D_; d += 4) {
                        h0 += (double)(cold[d + 0] * w1r[d + 0]);
                        h1 += (double)(cold[d + 1] * w1r[d + 1]);
                        h2 += (double)(cold[d + 2] * w1r[d + 2]);
                        h3 += (double)(cold[d + 3] * w1r[d + 3]);
                    }
                    float h = (float)((h0 + h1) + (h2 + h3)) + b1p[j];
                    h = fmaxf(h, 0.0f);
                    const float* w2row = &sw2t[jj][0];
                    #pragma unroll
                    for (int d = 0; d < D_; ++d)
                        dacc[d] += (double)(h * w2row[d]);
                }
            }
            // C = (C + T) + b2, f32 adds in reference order
            #pragma unroll
            for (int d = 0; d < D_; ++d)
                cold[d] = (cold[d] + (float)dacc[d]) + b2p[d];
        }

        // ---- distances (f64 sum of f32 squares) + argmin ----
        {
            double q0 = 0, q1 = 0, q2 = 0, q3 = 0;
            #pragma unroll
            for (int d = 0; d < D_; d += 4) {
                float e0 = sr[d + 0] - cold[d + 0]; q0 += (double)(e0 * e0);
                float e1 = sr[d + 1] - cold[d + 1]; q1 += (double)(e1 * e1);
                float e2 = sr[d + 2] - cold[d + 2]; q2 += (double)(e2 * e2);
                float e3 = sr[d + 3] - cold[d + 3]; q3 += (double)(e3 * e3);
            }
            sdist[k] = (float)((q0 + q1) + (q2 + q3));
        }
        __syncthreads();

        if (t == 0) {
            float best = sdist[0];
            int bidx = 0;
            for (int kk = 1; kk < K_; ++kk) {
                float v = sdist[kk];
                if (v < best) { best = v; bidx = kk; }   // first-min tie-break
            }
            scode = bidx;
            out1[(size_t)n * M_ + m] = (float)bidx;
        }
        __syncthreads();

        if (k == scode) {
            #pragma unroll
            for (int d = 0; d < D_; ++d) scsel[d] = cold[d];
        }
        __syncthreads();

        if (t < D_) {
            float cs = scsel[t];
            out3[((size_t)m * N_ + n) * D_ + t] = cs;
            float xnew = sxhat[t] + cs;
            sxhat[t] = xnew;
            if (m == M_ - 1) {
                float zv = z[n * D_ + t];
                out0[(size_t)n * D_ + t] = zv + (xnew - zv);
            }
        }
        __syncthreads();
    }
}

extern "C" void kernel_launch(void* const* d_in, const int* in_sizes, int n_in,
                              void* d_out, int out_size, void* d_ws, size_t ws_size,
                              hipStream_t stream) {
    const float* z       = (const float*)d_in[0];
    const float* base_cb = (const float*)d_in[1];
    const float* cp_w    = (const float*)d_in[2];
    const float* cp_b    = (const float*)d_in[3];
    const float* w1      = (const float*)d_in[4];
    const float* b1      = (const float*)d_in[5];
    const float* w2      = (const float*)d_in[6];
    const float* b2      = (const float*)d_in[7];

    float* out  = (float*)d_out;
    float* out0 = out;                         // (N,D)
    float* out1 = out0 + (size_t)N_ * D_;      // (N,M)
    float* out2 = out1 + (size_t)N_ * M_;      // (M,N,D)
    float* out3 = out2 + (size_t)M_ * N_ * D_; // (M,N,D)

    float* Bb = (float*)d_ws;                  // M*K*D floats = 512 KB

    hipLaunchKernelGGL(precompute_Bb, dim3(M_ * K_), dim3(D_), 0, stream,
                       base_cb, cp_w, Bb);
    hipLaunchKernelGGL(qinco_main, dim3(N_), dim3(K_), 0, stream,
                       z, cp_w, cp_b, w1, b1, w2, b2, Bb,
                       out0, out1, out2, out3);
}

// Round 3
// 5095.396 us; speedup vs baseline: 5.7314x; 5.7314x over previous
//
#include <hip/hip_runtime.h>

#define N_ 1024
#define D_ 128
#define K_ 256
#define M_ 4
#define H_ 256
#define NB_ 2
#define KT_ 32    // k-tile rows
#define NKT_ 8    // K_/KT_

using f32x4 = __attribute__((ext_vector_type(4))) float;
using f64x2 = __attribute__((ext_vector_type(2))) double;
using f64x4 = __attribute__((ext_vector_type(4))) double;

// ---------------------------------------------------------------------------
// Kernel 1: Bb[m,k,d] = f32( exact_sum_d' cb[k,d'] * cp_w[m,d,D+d'] )
// ---------------------------------------------------------------------------
__global__ void precompute_Bb(const float* __restrict__ base_cb,
                              const float* __restrict__ cp_w,
                              float* __restrict__ Bb) {
    const int mk = blockIdx.x;          // m*K + k
    const int m  = mk >> 8;
    const int d  = threadIdx.x;         // 0..127
    const float* cb = base_cb + (size_t)mk * D_;
    const float* wc = cp_w + ((size_t)(m * D_ + d)) * (2 * D_) + D_;
    double a0 = 0, a1 = 0, a2 = 0, a3 = 0;
    #pragma unroll
    for (int dp = 0; dp < D_; dp += 4) {
        a0 += (double)(cb[dp + 0] * wc[dp + 0]);
        a1 += (double)(cb[dp + 1] * wc[dp + 1]);
        a2 += (double)(cb[dp + 2] * wc[dp + 2]);
        a3 += (double)(cb[dp + 3] * wc[dp + 3]);
    }
    Bb[(size_t)mk * D_ + d] = (float)((a0 + a1) + (a2 + a3));
}

// ---------------------------------------------------------------------------
// Kernel 2: widen w1, w2 to f64 (layouts already match the MFMA B-frag needs:
// w1 [bi][j][d] with d contiguous; w2 [bi][d][j] with j contiguous).
// ---------------------------------------------------------------------------
__global__ void convert_w(const float* __restrict__ w1,
                          const float* __restrict__ w2,
                          double* __restrict__ w1f,
                          double* __restrict__ w2f) {
    const int i = blockIdx.x * blockDim.x + threadIdx.x;  // 0..262143
    w1f[i] = (double)w1[i];
    w2f[i] = (double)w2[i];
}

// ---------------------------------------------------------------------------
// Kernel 3: one workgroup per n. MLP via f64 MFMA on 32-row k-tiles.
// ---------------------------------------------------------------------------
__launch_bounds__(256, 2)
__global__ void qinco_main(const float* __restrict__ z,
                           const float* __restrict__ cp_w,
                           const float* __restrict__ cp_b,
                           const float* __restrict__ w1,
                           const float* __restrict__ b1,
                           const float* __restrict__ w2,
                           const float* __restrict__ b2,
                           const float* __restrict__ Bb,
                           const double* __restrict__ w1f64,
                           const double* __restrict__ w2f64,
                           float* __restrict__ out0,   // z_q_st  (N,D)
                           float* __restrict__ out1,   // codes   (N,M) as float
                           float* __restrict__ out2,   // residuals (M,N,D)
                           float* __restrict__ out3) { // centroids (M,N,D)
    __shared__ alignas(16) float sC[KT_][132];
    __shared__ alignas(16) float sH[KT_][260];
    __shared__ float sxhat[D_];
    __shared__ float sA[D_];
    __shared__ float sr[D_];
    __shared__ float scb[D_];
    __shared__ float scsel[D_];
    __shared__ float shrow[H_];
    __shared__ float sdist[K_];
    __shared__ int   scode;

    const int n    = blockIdx.x;
    const int t    = threadIdx.x;
    const int wid  = t >> 6;      // wave 0..3
    const int lane = t & 63;
    const int l15  = lane & 15;
    const int q    = lane >> 4;   // 0..3

    if (t < D_) sxhat[t] = 0.0f;
    __syncthreads();

    for (int m = 0; m < M_; ++m) {
        // ---- r = z - x_hat ; A = x_hat @ Wx^T (f64 sums) ; stage cp_b ----
        if (t < D_) {
            scb[t] = cp_b[m * D_ + t];
            const float zv = z[(size_t)n * D_ + t];
            const float rv = zv - sxhat[t];
            sr[t] = rv;
            out2[((size_t)m * N_ + n) * D_ + t] = rv;
            const float* wx = cp_w + ((size_t)(m * D_ + t)) * (2 * D_);
            const f32x4* wp = (const f32x4*)wx;
            double a0 = 0, a1 = 0, a2 = 0, a3 = 0;
            #pragma unroll 8
            for (int u = 0; u < 32; ++u) {
                f32x4 wv = wp[u];
                a0 += (double)(sxhat[u * 4 + 0] * wv[0]);
                a1 += (double)(sxhat[u * 4 + 1] * wv[1]);
                a2 += (double)(sxhat[u * 4 + 2] * wv[2]);
                a3 += (double)(sxhat[u * 4 + 3] * wv[3]);
            }
            sA[t] = (float)((a0 + a1) + (a2 + a3));
        }
        __syncthreads();

        // ---- k-tiles: C init -> 2x (MFMA layer1, layer2) -> dists ----
        for (int kt = 0; kt < NKT_; ++kt) {
            const int k0 = kt * KT_;

            // C init: C[k][d] = (A[d] + Bb[m][k0+k][d]) + cp_b[d]
            {
                const int row  = t >> 3;          // 0..31
                const int dblk = (t & 7) * 16;    // 16 floats per thread
                const f32x4* bb4 = (const f32x4*)(Bb + ((size_t)(m * K_ + k0 + row)) * D_ + dblk);
                #pragma unroll
                for (int u = 0; u < 4; ++u) {
                    f32x4 bv = bb4[u];
                    #pragma unroll
                    for (int x = 0; x < 4; ++x) {
                        const int d = dblk + u * 4 + x;
                        sC[row][d] = (sA[d] + bv[x]) + scb[d];
                    }
                }
            }
            __syncthreads();

            for (int i = 0; i < NB_; ++i) {
                const int bi = m * NB_ + i;

                // ---- phase 1: h = relu(f32(C @ W1^T) + b1) ----
                {
                    const double* w1b = w1f64 + (size_t)bi * H_ * D_;
                    const float*  b1b = b1 + (size_t)bi * H_;
                    const int jbase = wid * 64;
                    #pragma unroll
                    for (int nt = 0; nt < 4; ++nt) {
                        const int jcol = jbase + nt * 16 + l15;
                        const f64x2* bp = (const f64x2*)(w1b + (size_t)jcol * D_ + 32 * q);
                        f64x2 bv[16];
                        #pragma unroll
                        for (int u = 0; u < 16; ++u) bv[u] = bp[u];
                        const float b1v = b1b[jcol];
                        #pragma unroll
                        for (int mt = 0; mt < 2; ++mt) {
                            const int r0 = mt * 16 + l15;
                            const f32x4* ap = (const f32x4*)&sC[r0][32 * q];
                            f32x4 av[8];
                            #pragma unroll
                            for (int u = 0; u < 8; ++u) av[u] = ap[u];
                            f64x4 acc = {0.0, 0.0, 0.0, 0.0};
                            #pragma unroll
                            for (int s = 0; s < 32; ++s)
                                acc = __builtin_amdgcn_mfma_f64_16x16x4f64(
                                    (double)av[s / 4][s % 4], bv[s / 2][s % 2], acc, 0, 0, 0);
                            #pragma unroll
                            for (int qq = 0; qq < 4; ++qq) {
                                float hv = (float)acc[qq] + b1v;
                                sH[mt * 16 + q * 4 + qq][jcol] = fmaxf(hv, 0.0f);
                            }
                        }
                    }
                }
                __syncthreads();

                // ---- phase 2: C = (C + f32(h @ W2^T)) + b2 ----
                {
                    const double* w2b = w2f64 + (size_t)bi * D_ * H_;
                    const float*  b2b = b2 + (size_t)bi * D_;
                    const int dbase = wid * 32;
                    #pragma unroll
                    for (int nt = 0; nt < 2; ++nt) {
                        const int dcol = dbase + nt * 16 + l15;
                        const double* w2p = w2b + (size_t)dcol * H_ + 64 * q;
                        const float b2v = b2b[dcol];
                        f64x4 acc[2];
                        acc[0] = (f64x4){0.0, 0.0, 0.0, 0.0};
                        acc[1] = (f64x4){0.0, 0.0, 0.0, 0.0};
                        #pragma unroll
                        for (int half = 0; half < 2; ++half) {
                            const f64x2* bp = (const f64x2*)(w2p + 32 * half);
                            f64x2 bv[16];
                            #pragma unroll
                            for (int u = 0; u < 16; ++u) bv[u] = bp[u];
                            #pragma unroll
                            for (int mt = 0; mt < 2; ++mt) {
                                const int r0 = mt * 16 + l15;
                                const f32x4* hp = (const f32x4*)&sH[r0][64 * q + 32 * half];
                                f32x4 av[8];
                                #pragma unroll
                                for (int u = 0; u < 8; ++u) av[u] = hp[u];
                                #pragma unroll
                                for (int s = 0; s < 32; ++s)
                                    acc[mt] = __builtin_amdgcn_mfma_f64_16x16x4f64(
                                        (double)av[s / 4][s % 4], bv[s / 2][s % 2], acc[mt], 0, 0, 0);
                            }
                        }
                        #pragma unroll
                        for (int mt = 0; mt < 2; ++mt) {
                            #pragma unroll
                            for (int qq = 0; qq < 4; ++qq) {
                                const int r = mt * 16 + q * 4 + qq;
                                const float cv = sC[r][dcol];
                                sC[r][dcol] = (cv + (float)acc[mt][qq]) + b2v;
                            }
                        }
                    }
                }
                __syncthreads();
            }

            // ---- dists for this tile (f32 squares, exact f64 sum) ----
            if (t < 128) {
                const int row = t >> 2;       // 0..31
                const int seg = t & 3;        // 32 d's each
                double qacc = 0.0;
                #pragma unroll
                for (int dd = 0; dd < 32; ++dd) {
                    const int d = seg * 32 + dd;
                    const float e = sr[d] - sC[row][d];
                    const float e2 = e * e;
                    qacc += (double)e2;
                }
                qacc += __shfl_xor(qacc, 1);
                qacc += __shfl_xor(qacc, 2);
                if (seg == 0) sdist[k0 + row] = (float)qacc;
            }
            __syncthreads();
        }

        // ---- argmin (first-occurrence tie-break) ----
        if (t == 0) {
            float best = sdist[0];
            int bidx = 0;
            for (int kk = 1; kk < K_; ++kk) {
                const float v = sdist[kk];
                if (v < best) { best = v; bidx = kk; }
            }
            scode = bidx;
            out1[(size_t)n * M_ + m] = (float)bidx;
        }
        __syncthreads();

        // ---- recompute selected row exactly (VALU, R2 semantics) ----
        const int code = scode;
        if (t < D_)
            scsel[t] = (sA[t] + Bb[((size_t)(m * K_ + code)) * D_ + t]) + scb[t];
        __syncthreads();

        for (int i = 0; i < NB_; ++i) {
            const int bi = m * NB_ + i;
            {   // h[j], j = t
                const f32x4* wp = (const f32x4*)(w1 + ((size_t)bi * H_ + t) * D_);
                double h0 = 0, h1 = 0, h2 = 0, h3 = 0;
                #pragma unroll 8
                for (int u = 0; u < 32; ++u) {
                    f32x4 wv = wp[u];
                    h0 += (double)(scsel[u * 4 + 0] * wv[0]);
                    h1 += (double)(scsel[u * 4 + 1] * wv[1]);
                    h2 += (double)(scsel[u * 4 + 2] * wv[2]);
                    h3 += (double)(scsel[u * 4 + 3] * wv[3]);
                }
                float hv = (float)((h0 + h1) + (h2 + h3)) + b1[(size_t)bi * H_ + t];
                shrow[t] = fmaxf(hv, 0.0f);
            }
            __syncthreads();
            if (t < D_) {
                const f32x4* wp = (const f32x4*)(w2 + ((size_t)bi * D_ + t) * H_);
                double s0 = 0, s1 = 0, s2 = 0, s3 = 0;
                #pragma unroll 8
                for (int u = 0; u < 64; ++u) {
                    f32x4 wv = wp[u];
                    s0 += (double)(shrow[u * 4 + 0] * wv[0]);
                    s1 += (double)(shrow[u * 4 + 1] * wv[1]);
                    s2 += (double)(shrow[u * 4 + 2] * wv[2]);
                    s3 += (double)(shrow[u * 4 + 3] * wv[3]);
                }
                const float Tv = (float)((s0 + s1) + (s2 + s3));
                scsel[t] = (scsel[t] + Tv) + b2[(size_t)bi * D_ + t];
            }
            __syncthreads();
        }

        // ---- outputs + x_hat update ----
        if (t < D_) {
            const float cs = scsel[t];
            out3[((size_t)m * N_ + n) * D_ + t] = cs;
            const float xnew = sxhat[t] + cs;
            sxhat[t] = xnew;
            if (m == M_ - 1) {
                const float zv = z[(size_t)n * D_ + t];
                out0[(size_t)n * D_ + t] = zv + (xnew - zv);
            }
        }
        __syncthreads();
    }
}

extern "C" void kernel_launch(void* const* d_in, const int* in_sizes, int n_in,
                              void* d_out, int out_size, void* d_ws, size_t ws_size,
                              hipStream_t stream) {
    const float* z       = (const float*)d_in[0];
    const float* base_cb = (const float*)d_in[1];
    const float* cp_w    = (const float*)d_in[2];
    const float* cp_b    = (const float*)d_in[3];
    const float* w1      = (const float*)d_in[4];
    const float* b1      = (const float*)d_in[5];
    const float* w2      = (const float*)d_in[6];
    const float* b2      = (const float*)d_in[7];

    float* out  = (float*)d_out;
    float* out0 = out;                          // (N,D)
    float* out1 = out0 + (size_t)N_ * D_;       // (N,M)
    float* out2 = out1 + (size_t)N_ * M_;       // (M,N,D)
    float* out3 = out2 + (size_t)M_ * N_ * D_;  // (M,N,D)

    // ws: Bb (512 KB f32) | w1f64 (2 MB) | w2f64 (2 MB)
    float*  Bb    = (float*)d_ws;
    double* w1f64 = (double*)((char*)d_ws + 524288);
    double* w2f64 = (double*)((char*)d_ws + 524288 + 2097152);

    hipLaunchKernelGGL(precompute_Bb, dim3(M_ * K_), dim3(D_), 0, stream,
                       base_cb, cp_w, Bb);
    hipLaunchKernelGGL(convert_w, dim3(1024), dim3(256), 0, stream,
                       w1, w2, w1f64, w2f64);
    hipLaunchKernelGGL(qinco_main, dim3(N_), dim3(256), 0, stream,
                       z, cp_w, cp_b, w1, b1, w2, b2, Bb, w1f64, w2f64,
                       out0, out1, out2, out3);
}

// Round 4
// 2538.745 us; speedup vs baseline: 11.5032x; 2.0071x over previous
//
#include <hip/hip_runtime.h>

#define N_ 1024
#define D_ 128
#define K_ 256
#define M_ 4
#define H_ 256
#define NB_ 2
#define KT_ 32
#define NKT_ 8
#define EPS_ 0.2f

#define CPAD 132
#define CHPAD 136
#define HPAD 264

typedef __attribute__((ext_vector_type(8))) short short8;
typedef __attribute__((ext_vector_type(4))) float f32x4;

__device__ inline unsigned short f32_to_bf16_rne(float x) {
    unsigned u = __float_as_uint(x);
    unsigned r = u + 0x7FFFu + ((u >> 16) & 1u);
    return (unsigned short)(r >> 16);
}
__device__ inline void split2(float x, unsigned short& hi, unsigned short& lo) {
    unsigned u = __float_as_uint(x) & 0xFFFF0000u;
    hi = (unsigned short)(u >> 16);
    lo = f32_to_bf16_rne(x - __uint_as_float(u));
}

// ---------------------------------------------------------------------------
// Kernel 1: Bb[m,k,d] = f32( exact_sum_d' cb[k,d'] * cp_w[m,d,D+d'] )
// ---------------------------------------------------------------------------
__global__ void precompute_Bb(const float* __restrict__ base_cb,
                              const float* __restrict__ cp_w,
                              float* __restrict__ Bb) {
    const int mk = blockIdx.x;
    const int m  = mk >> 8;
    const int d  = threadIdx.x;
    const float* cb = base_cb + (size_t)mk * D_;
    const float* wc = cp_w + ((size_t)(m * D_ + d)) * (2 * D_) + D_;
    double a0 = 0, a1 = 0, a2 = 0, a3 = 0;
    #pragma unroll
    for (int dp = 0; dp < D_; dp += 4) {
        a0 += (double)(cb[dp + 0] * wc[dp + 0]);
        a1 += (double)(cb[dp + 1] * wc[dp + 1]);
        a2 += (double)(cb[dp + 2] * wc[dp + 2]);
        a3 += (double)(cb[dp + 3] * wc[dp + 3]);
    }
    Bb[(size_t)mk * D_ + d] = (float)((a0 + a1) + (a2 + a3));
}

// ---------------------------------------------------------------------------
// Kernel 2: split w1, w2 into bf16 hi/lo pairs.
// ---------------------------------------------------------------------------
__global__ void convert_w(const float* __restrict__ w1,
                          const float* __restrict__ w2,
                          unsigned short* __restrict__ w1h,
                          unsigned short* __restrict__ w1l,
                          unsigned short* __restrict__ w2h,
                          unsigned short* __restrict__ w2l) {
    const int i = blockIdx.x * blockDim.x + threadIdx.x; // 0..262143
    unsigned short h, l;
    split2(w1[i], h, l); w1h[i] = h; w1l[i] = l;
    split2(w2[i], h, l); w2h[i] = h; w2l[i] = l;
}

// ---------------------------------------------------------------------------
// Kernel 3: one workgroup per n. Fast bf16-split MFMA distances + exact
// f64 refinement of near-minimal candidates.
// ---------------------------------------------------------------------------
__launch_bounds__(256, 2)
__global__ void qinco_main(const float* __restrict__ z,
                           const float* __restrict__ cp_w,
                           const float* __restrict__ cp_b,
                           const float* __restrict__ w1,
                           const float* __restrict__ b1,
                           const float* __restrict__ w2,
                           const float* __restrict__ b2,
                           const float* __restrict__ Bb,
                           const unsigned short* __restrict__ w1hi,
                           const unsigned short* __restrict__ w1lo,
                           const unsigned short* __restrict__ w2hi,
                           const unsigned short* __restrict__ w2lo,
                           float* __restrict__ out0,   // z_q_st  (N,D)
                           float* __restrict__ out1,   // codes   (N,M)
                           float* __restrict__ out2,   // residuals (M,N,D)
                           float* __restrict__ out3) { // centroids (M,N,D)
    __shared__ alignas(16) float sC[KT_][CPAD];
    __shared__ alignas(16) unsigned short sChi[KT_][CHPAD];
    __shared__ alignas(16) unsigned short sClo[KT_][CHPAD];
    __shared__ alignas(16) unsigned short sHhi[KT_][HPAD];
    __shared__ alignas(16) unsigned short sHlo[KT_][HPAD];
    __shared__ float sxhat[D_], sA[D_], sr[D_], scb[D_], scsel[D_], sE[D_];
    __shared__ float shrow[H_];
    __shared__ float sdist[K_];
    __shared__ int   sflag[K_];
    __shared__ double sdd[2];
    __shared__ float smin, sbest;
    __shared__ int   sbidx, supd;

    const int n    = blockIdx.x;
    const int t    = threadIdx.x;
    const int wid  = t >> 6;
    const int lane = t & 63;
    const int l15  = lane & 15;
    const int q    = lane >> 4;

    if (t < D_) sxhat[t] = 0.0f;
    __syncthreads();

    for (int m = 0; m < M_; ++m) {
        // ---- r, A (exact), stage cp_b ----
        if (t < D_) {
            scb[t] = cp_b[m * D_ + t];
            const float zv = z[(size_t)n * D_ + t];
            const float rv = zv - sxhat[t];
            sr[t] = rv;
            out2[((size_t)m * N_ + n) * D_ + t] = rv;
            const f32x4* wp = (const f32x4*)(cp_w + ((size_t)(m * D_ + t)) * (2 * D_));
            double a0 = 0, a1 = 0, a2 = 0, a3 = 0;
            #pragma unroll 8
            for (int u = 0; u < 32; ++u) {
                f32x4 wv = wp[u];
                a0 += (double)(sxhat[u * 4 + 0] * wv[0]);
                a1 += (double)(sxhat[u * 4 + 1] * wv[1]);
                a2 += (double)(sxhat[u * 4 + 2] * wv[2]);
                a3 += (double)(sxhat[u * 4 + 3] * wv[3]);
            }
            sA[t] = (float)((a0 + a1) + (a2 + a3));
        }
        __syncthreads();

        // ================= FAST PATH: distances via bf16-split MFMA ========
        for (int kt = 0; kt < NKT_; ++kt) {
            const int k0 = kt * KT_;

            // C init + split
            {
                const int row  = t >> 3;
                const int dblk = (t & 7) * 16;
                const f32x4* bb4 = (const f32x4*)(Bb + ((size_t)(m * K_ + k0 + row)) * D_ + dblk);
                #pragma unroll
                for (int u = 0; u < 4; ++u) {
                    f32x4 bv = bb4[u];
                    #pragma unroll
                    for (int x = 0; x < 4; ++x) {
                        const int d = dblk + u * 4 + x;
                        const float cv = (sA[d] + bv[x]) + scb[d];
                        sC[row][d] = cv;
                        unsigned short ch, cl;
                        split2(cv, ch, cl);
                        sChi[row][d] = ch;
                        sClo[row][d] = cl;
                    }
                }
            }
            __syncthreads();

            for (int i = 0; i < NB_; ++i) {
                const int bi = m * NB_ + i;

                // ---- GEMM1: h = relu(C @ W1^T + b1) ----
                {
                    const unsigned short* w1h = w1hi + (size_t)bi * H_ * D_;
                    const unsigned short* w1l = w1lo + (size_t)bi * H_ * D_;
                    #pragma unroll
                    for (int u = 0; u < 4; ++u) {
                        const int jcol = (wid * 4 + u) * 16 + l15;
                        const size_t wbase = (size_t)jcol * D_ + q * 8;
                        short8 bh[4], bl[4];
                        #pragma unroll
                        for (int kk = 0; kk < 4; ++kk) {
                            bh[kk] = *(const short8*)(w1h + wbase + kk * 32);
                            bl[kk] = *(const short8*)(w1l + wbase + kk * 32);
                        }
                        const float b1v = b1[(size_t)bi * H_ + jcol];
                        #pragma unroll
                        for (int mt = 0; mt < 2; ++mt) {
                            const int r = mt * 16 + l15;
                            f32x4 acc = {0.f, 0.f, 0.f, 0.f};
                            #pragma unroll
                            for (int kk = 0; kk < 4; ++kk) {
                                short8 ah = *(const short8*)&sChi[r][kk * 32 + q * 8];
                                short8 al = *(const short8*)&sClo[r][kk * 32 + q * 8];
                                acc = __builtin_amdgcn_mfma_f32_16x16x32_bf16(ah, bh[kk], acc, 0, 0, 0);
                                acc = __builtin_amdgcn_mfma_f32_16x16x32_bf16(ah, bl[kk], acc, 0, 0, 0);
                                acc = __builtin_amdgcn_mfma_f32_16x16x32_bf16(al, bh[kk], acc, 0, 0, 0);
                            }
                            #pragma unroll
                            for (int qq = 0; qq < 4; ++qq) {
                                const float hv = fmaxf(acc[qq] + b1v, 0.0f);
                                unsigned short hh, hl;
                                split2(hv, hh, hl);
                                sHhi[mt * 16 + q * 4 + qq][jcol] = hh;
                                sHlo[mt * 16 + q * 4 + qq][jcol] = hl;
                            }
                        }
                    }
                }
                __syncthreads();

                // ---- GEMM2: C = (C + h @ W2^T) + b2 ----
                {
                    const unsigned short* w2h = w2hi + (size_t)bi * D_ * H_;
                    const unsigned short* w2l = w2lo + (size_t)bi * D_ * H_;
                    #pragma unroll
                    for (int u = 0; u < 2; ++u) {
                        const int dcol = (wid * 2 + u) * 16 + l15;
                        const float b2v = b2[(size_t)bi * D_ + dcol];
                        const size_t wbase = (size_t)dcol * H_ + q * 8;
                        f32x4 acc0 = {0.f, 0.f, 0.f, 0.f};
                        f32x4 acc1 = {0.f, 0.f, 0.f, 0.f};
                        #pragma unroll
                        for (int kk = 0; kk < 8; ++kk) {
                            short8 bh = *(const short8*)(w2h + wbase + kk * 32);
                            short8 bl = *(const short8*)(w2l + wbase + kk * 32);
                            short8 ah0 = *(const short8*)&sHhi[l15][kk * 32 + q * 8];
                            short8 al0 = *(const short8*)&sHlo[l15][kk * 32 + q * 8];
                            acc0 = __builtin_amdgcn_mfma_f32_16x16x32_bf16(ah0, bh, acc0, 0, 0, 0);
                            acc0 = __builtin_amdgcn_mfma_f32_16x16x32_bf16(ah0, bl, acc0, 0, 0, 0);
                            acc0 = __builtin_amdgcn_mfma_f32_16x16x32_bf16(al0, bh, acc0, 0, 0, 0);
                            short8 ah1 = *(const short8*)&sHhi[16 + l15][kk * 32 + q * 8];
                            short8 al1 = *(const short8*)&sHlo[16 + l15][kk * 32 + q * 8];
                            acc1 = __builtin_amdgcn_mfma_f32_16x16x32_bf16(ah1, bh, acc1, 0, 0, 0);
                            acc1 = __builtin_amdgcn_mfma_f32_16x16x32_bf16(ah1, bl, acc1, 0, 0, 0);
                            acc1 = __builtin_amdgcn_mfma_f32_16x16x32_bf16(al1, bh, acc1, 0, 0, 0);
                        }
                        #pragma unroll
                        for (int qq = 0; qq < 4; ++qq) {
                            const int r = q * 4 + qq;
                            const float cv = (sC[r][dcol] + acc0[qq]) + b2v;
                            sC[r][dcol] = cv;
                            unsigned short ch, cl;
                            split2(cv, ch, cl);
                            sChi[r][dcol] = ch;
                            sClo[r][dcol] = cl;
                        }
                        #pragma unroll
                        for (int qq = 0; qq < 4; ++qq) {
                            const int r = 16 + q * 4 + qq;
                            const float cv = (sC[r][dcol] + acc1[qq]) + b2v;
                            sC[r][dcol] = cv;
                            unsigned short ch, cl;
                            split2(cv, ch, cl);
                            sChi[r][dcol] = ch;
                            sClo[r][dcol] = cl;
                        }
                    }
                }
                __syncthreads();
            }

            // ---- fast dists for this tile ----
            if (t < 128) {
                const int row = t >> 2, seg = t & 3;
                float qa = 0.f;
                #pragma unroll
                for (int dd = 0; dd < 32; ++dd) {
                    const int d = seg * 32 + dd;
                    const float e = sr[d] - sC[row][d];
                    qa = fmaf(e, e, qa);
                }
                qa += __shfl_xor(qa, 1);
                qa += __shfl_xor(qa, 2);
                if (seg == 0) sdist[k0 + row] = qa;
            }
            __syncthreads();
        }

        // ---- fast min (value-first, index tie-break) ----
        if (t < 64) {
            float bv = 1e30f; int bx = 0;
            #pragma unroll
            for (int u = 0; u < 4; ++u) {
                const int idx = t * 4 + u;
                const float v = sdist[idx];
                if (v < bv) { bv = v; bx = idx; }
            }
            #pragma unroll
            for (int s = 1; s < 64; s <<= 1) {
                const float ov = __shfl_xor(bv, s);
                const int   ox = __shfl_xor(bx, s);
                if (ov < bv || (ov == bv && ox < bx)) { bv = ov; bx = ox; }
            }
            if (t == 0) smin = bv;
        }
        __syncthreads();
        sflag[t] = (sdist[t] <= smin + EPS_) ? 1 : 0;
        if (t == 0) { sbest = 1e30f; sbidx = 0; }
        __syncthreads();

        // ============ EXACT refinement of candidates (R2 semantics) =========
        for (int k = 0; k < K_; ++k) {
            if (!sflag[k]) continue;   // uniform branch (LDS broadcast)
            if (t < D_)
                sE[t] = (sA[t] + Bb[((size_t)(m * K_ + k)) * D_ + t]) + scb[t];
            __syncthreads();
            for (int i = 0; i < NB_; ++i) {
                const int bi = m * NB_ + i;
                {
                    const f32x4* wp = (const f32x4*)(w1 + ((size_t)bi * H_ + t) * D_);
                    double h0 = 0, h1 = 0, h2 = 0, h3 = 0;
                    #pragma unroll 8
                    for (int u = 0; u < 32; ++u) {
                        f32x4 wv = wp[u];
                        h0 += (double)(sE[u * 4 + 0] * wv[0]);
                        h1 += (double)(sE[u * 4 + 1] * wv[1]);
                        h2 += (double)(sE[u * 4 + 2] * wv[2]);
                        h3 += (double)(sE[u * 4 + 3] * wv[3]);
                    }
                    const float hv = (float)((h0 + h1) + (h2 + h3)) + b1[(size_t)bi * H_ + t];
                    shrow[t] = fmaxf(hv, 0.0f);
                }
                __syncthreads();
                if (t < D_) {
                    const f32x4* wp = (const f32x4*)(w2 + ((size_t)bi * D_ + t) * H_);
                    double s0 = 0, s1 = 0, s2 = 0, s3 = 0;
                    #pragma unroll 8
                    for (int u = 0; u < 64; ++u) {
                        f32x4 wv = wp[u];
                        s0 += (double)(shrow[u * 4 + 0] * wv[0]);
                        s1 += (double)(shrow[u * 4 + 1] * wv[1]);
                        s2 += (double)(shrow[u * 4 + 2] * wv[2]);
                        s3 += (double)(shrow[u * 4 + 3] * wv[3]);
                    }
                    sE[t] = (sE[t] + (float)((s0 + s1) + (s2 + s3))) + b2[(size_t)bi * D_ + t];
                }
                __syncthreads();
            }
            // exact distance
            {
                double dp = 0.0;
                if (t < D_) {
                    const float e = sr[t] - sE[t];
                    const float e2 = e * e;
                    dp = (double)e2;
                    #pragma unroll
                    for (int s = 1; s < 64; s <<= 1) dp += __shfl_xor(dp, s);
                    if ((t & 63) == 0) sdd[t >> 6] = dp;
                }
            }
            __syncthreads();
            if (t == 0) {
                const float df = (float)(sdd[0] + sdd[1]);
                if (df < sbest) { sbest = df; sbidx = k; supd = 1; }
                else supd = 0;
            }
            __syncthreads();
            if (supd && t < D_) scsel[t] = sE[t];
            __syncthreads();
        }

        if (t == 0) out1[(size_t)n * M_ + m] = (float)sbidx;

        // ---- outputs + x_hat update ----
        if (t < D_) {
            const float cs = scsel[t];
            out3[((size_t)m * N_ + n) * D_ + t] = cs;
            const float xnew = sxhat[t] + cs;
            sxhat[t] = xnew;
            if (m == M_ - 1) {
                const float zv = z[(size_t)n * D_ + t];
                out0[(size_t)n * D_ + t] = zv + (xnew - zv);
            }
        }
        __syncthreads();
    }
}

extern "C" void kernel_launch(void* const* d_in, const int* in_sizes, int n_in,
                              void* d_out, int out_size, void* d_ws, size_t ws_size,
                              hipStream_t stream) {
    const float* z       = (const float*)d_in[0];
    const float* base_cb = (const float*)d_in[1];
    const float* cp_w    = (const float*)d_in[2];
    const float* cp_b    = (const float*)d_in[3];
    const float* w1      = (const float*)d_in[4];
    const float* b1      = (const float*)d_in[5];
    const float* w2      = (const float*)d_in[6];
    const float* b2      = (const float*)d_in[7];

    float* out  = (float*)d_out;
    float* out0 = out;
    float* out1 = out0 + (size_t)N_ * D_;
    float* out2 = out1 + (size_t)N_ * M_;
    float* out3 = out2 + (size_t)M_ * N_ * D_;

    // ws: Bb 512K | w1hi 512K | w1lo 512K | w2hi 512K | w2lo 512K
    float*          Bb   = (float*)d_ws;
    unsigned short* w1hi = (unsigned short*)((char*)d_ws + 524288);
    unsigned short* w1lo = (unsigned short*)((char*)d_ws + 1048576);
    unsigned short* w2hi = (unsigned short*)((char*)d_ws + 1572864);
    unsigned short* w2lo = (unsigned short*)((char*)d_ws + 2097152);

    hipLaunchKernelGGL(precompute_Bb, dim3(M_ * K_), dim3(D_), 0, stream,
                       base_cb, cp_w, Bb);
    hipLaunchKernelGGL(convert_w, dim3(1024), dim3(256), 0, stream,
                       w1, w2, w1hi, w1lo, w2hi, w2lo);
    hipLaunchKernelGGL(qinco_main, dim3(N_), dim3(256), 0, stream,
                       z, cp_w, cp_b, w1, b1, w2, b2, Bb,
                       w1hi, w1lo, w2hi, w2lo,
                       out0, out1, out2, out3);
}